// Round 7
// baseline (155.673 us; speedup 1.0000x reference)
//
#include <hip/hip_runtime.h>
#include <hip/hip_fp16.h>
#include <math.h>

#define HW    25600
#define WID   160
#define HEI   160
#define BB    4
#define CIN   64
#define COUT  64
#define NBN   102400
#define TSTR  162     // p0 LDS tile stride in shorts: int-stride 81 == 17 mod 32

typedef _Float16 f16x8 __attribute__((ext_vector_type(8)));
typedef float    f32x4 __attribute__((ext_vector_type(4)));

union U4 { int i[4]; f16x8 v; };
union HU { unsigned u; __half2 h; };

__device__ __forceinline__ unsigned short f2h(float f) {
    return __half_as_ushort(__float2half(f));   // RNE
}

// ---------------------------------------------------------------------------
// P0: prep. blocks 0..639: transpose x[b][c][h][w] fp32 -> xbT[b][h][w][c] fp16
//     (float4 reads, LDS [c][w] stride-162 tile, paired-int phases)
//     block 640: pack w_def + w_off(odd) into MFMA A-fragment order (f16) + zero stats
// ---------------------------------------------------------------------------
__global__ __launch_bounds__(256) void p0_prep(
        const float* __restrict__ x, const float* __restrict__ w_def,
        const float* __restrict__ w_off,
        unsigned short* __restrict__ xbT, unsigned short* __restrict__ wtA,
        unsigned short* __restrict__ wofA, float* __restrict__ stats) {
    int t = threadIdx.x;
    int blk = blockIdx.x;
    if (blk == 640) {
        for (int u = 0; u < 144; ++u) {
            int idx = t + u * 256;                 // < 36864
            int k = idx >> 12;
            int r = idx & 4095;
            int chalf = r >> 11;
            int og = (r >> 9) & 3;
            int L = (r >> 3) & 63;
            int j = idx & 7;
            int o = og * 16 + (L & 15);
            int c = chalf * 32 + (L >> 4) * 8 + j;
            wtA[idx] = f2h(w_def[(o * CIN + c) * 9 + k]);
        }
        for (int u = 0; u < 36; ++u) {
            int idx = t + u * 256;                 // < 9216
            int jj = idx & 7;
            int L  = (idx >> 3) & 63;
            int ch = (idx >> 9) & 1;
            int k  = idx >> 10;
            int j  = L & 15;
            int c  = ch * 32 + (L >> 4) * 8 + jj;
            wofA[idx] = (j < 9) ? f2h(w_off[((2 * j + 1) * CIN + c) * 9 + k])
                                : (unsigned short)0;
        }
        if (t < 32) stats[t] = 0.f;
        return;
    }
    __shared__ __align__(16) unsigned short tile[CIN * TSTR];  // [c][w]
    int b = blk / HEI, h = blk % HEI;
    const float* xp = x + (b * CIN) * HW + h * WID;
    unsigned* ti = (unsigned*)tile;
#pragma unroll
    for (int u = 0; u < 10; ++u) {
        int e = t + u * 256;                       // 0..2559 = 64 c x 40 quads
        int c = e / 40, wq = e - c * 40;
        const float4 v = *(const float4*)(xp + c * HW + 4 * wq);
        unsigned p01 = f2h(v.x) | ((unsigned)f2h(v.y) << 16);
        unsigned p23 = f2h(v.z) | ((unsigned)f2h(v.w) << 16);
        ti[81 * c + 2 * wq]     = p01;
        ti[81 * c + 2 * wq + 1] = p23;
    }
    __syncthreads();
    unsigned* dst = (unsigned*)(xbT + (b * HEI + h) * (WID * 64));
#pragma unroll
    for (int u = 0; u < 20; ++u) {
        int e = t + u * 256;                       // 0..5119 = 160 w x 32 cpair
        int w = e >> 5, cp = e & 31;
        unsigned lo = tile[(2 * cp) * TSTR + w];
        unsigned hi = tile[(2 * cp + 1) * TSTR + w];
        dst[e] = lo | (hi << 16);
    }
}

// ---------------------------------------------------------------------------
// K1: offset conv via f16 MFMA + fused bias + BN stats.
// ---------------------------------------------------------------------------
__global__ __launch_bounds__(256) void k1_offconv_mfma(
        const unsigned short* __restrict__ xbT,
        const unsigned short* __restrict__ wofA,
        const float* __restrict__ b_off,
        float* __restrict__ off_odd, float* __restrict__ stats) {
    int t = threadIdx.x;
    int blk = blockIdx.x;                          // 0..639
    int xcd = blk & 7;
    int idx = blk >> 3;                            // 0..79
    int b = idx / 20;
    int h = xcd * 20 + (idx - b * 20);
    int wave = t >> 6, lane = t & 63;
    int l15 = lane & 15, q = lane >> 4;

    int npx = (wave < 2) ? 3 : 2;
    f32x4 acc[3];
#pragma unroll
    for (int i = 0; i < 3; ++i) acc[i] = (f32x4){0.f, 0.f, 0.f, 0.f};

    int klo = 4 - h;   if (klo < 0) klo = 0;
    int khi = 163 - h; if (khi > 8) khi = 8;

    for (int k = klo; k <= khi; ++k) {
        int py = h + k - 4;
        const unsigned short* row = xbT + (b * HEI + py) * (WID * 64);
        f16x8 a0 = *(const f16x8*)(wofA + ((k * 2 + 0) * 64 + lane) * 8);
        f16x8 a1 = *(const f16x8*)(wofA + ((k * 2 + 1) * 64 + lane) * 8);
#pragma unroll
        for (int u = 0; u < 3; ++u) {
            if (u >= npx) break;
            int px = (wave + u * 4) * 16 + l15;
            const unsigned short* sp = row + px * 64;
            f16x8 b0 = *(const f16x8*)(sp + q * 8);
            f16x8 b1 = *(const f16x8*)(sp + 32 + q * 8);
            acc[u] = __builtin_amdgcn_mfma_f32_16x16x32_f16(a0, b0, acc[u], 0, 0, 0);
            acc[u] = __builtin_amdgcn_mfma_f32_16x16x32_f16(a1, b1, acc[u], 0, 0, 0);
        }
    }

    float sS[4] = {0.f, 0.f, 0.f, 0.f}, sQ[4] = {0.f, 0.f, 0.f, 0.f};
#pragma unroll
    for (int u = 0; u < 3; ++u) {
        if (u >= npx) break;
        int px = (wave + u * 4) * 16 + l15;
#pragma unroll
        for (int r = 0; r < 4; ++r) {
            int j = q * 4 + r;
            if (j < 9) {
                float v = acc[u][r] + b_off[2 * j + 1];
                off_odd[(b * 9 + j) * HW + h * WID + px] = v;
                sS[r] += v; sQ[r] += v * v;
            }
        }
    }
#pragma unroll
    for (int o = 1; o < 16; o <<= 1) {
#pragma unroll
        for (int r = 0; r < 4; ++r) {
            sS[r] += __shfl_xor(sS[r], o);
            sQ[r] += __shfl_xor(sQ[r], o);
        }
    }
    __shared__ float redS[4][16], redQ[4][16];
    if (l15 == 0) {
#pragma unroll
        for (int r = 0; r < 4; ++r) {
            int j = q * 4 + r;
            if (j < 9) { redS[wave][j] = sS[r]; redQ[wave][j] = sQ[r]; }
        }
    }
    __syncthreads();
    if (t < 18) {
        int j = (t < 9) ? t : t - 9;
        float v = (t < 9) ? redS[0][j] + redS[1][j] + redS[2][j] + redS[3][j]
                          : redQ[0][j] + redQ[1][j] + redQ[2][j] + redQ[3][j];
        atomicAdd(&stats[t], v);
    }
}

// ---------------------------------------------------------------------------
// K4 v5: deformable conv via f16 MFMA.
//  - packed-f16 lerp: 2 VALU per int-pair, no unpack/repack (was ~11 VALU)
//  - s0/s1 pre-packed as duplicated half2 in LDS
//  - batched register prefetch + double-buffered S, 1 barrier/tap
// ---------------------------------------------------------------------------
__global__ __launch_bounds__(256, 5) void k4_deform_mfma(
        const unsigned short* __restrict__ xbT,
        const float* __restrict__ off_odd,
        const float* __restrict__ stats,
        const float* __restrict__ gamma,
        const float* __restrict__ beta,
        const unsigned short* __restrict__ wtA,
        const float* __restrict__ b_def,
        float* __restrict__ out) {
    __shared__ __align__(16) int S[2][80 * 36];    // samples, frag layout, dbuf
    __shared__ unsigned P0h[9][80], P1h[9][80];    // packed (s,s) half2
    __shared__ int      PXI[9][80];                // xi0 | xi1<<16

    int t   = threadIdx.x;
    int blk = blockIdx.x;                          // 0..1279
    int xcd = blk & 7;
    int idx = blk >> 3;                            // 0..159
    int b   = idx / 40;
    int r2  = idx - b * 40;                        // 0..39
    int h   = xcd * 20 + (r2 >> 1);
    int half = r2 & 1;
    int p0  = half * 80;
    int wave = t >> 6, lane = t & 63;
    int l15 = lane & 15, q = lane >> 4;

    // ---- prep: offsets -> sampling params (fused BN+tanh+convert) ----
    if (t < 80) {
        int px = p0 + t;
        float tv[9];
#pragma unroll
        for (int j = 0; j < 9; ++j) {
            float mean = stats[j] * (1.0f / NBN);
            float var  = stats[9 + j] * (1.0f / NBN) - mean * mean;
            float inv  = rsqrtf(var + 1e-5f);
            float v = off_odd[(b * 9 + j) * HW + h * WID + px];
            tv[j] = tanhf((v - mean) * inv * gamma[2 * j + 1] + beta[2 * j + 1]);
        }
        float dxv[9];
        dxv[4] = tv[4];
#pragma unroll
        for (int i = 5; i < 9; ++i) dxv[i] = dxv[i - 1] + tv[i];
#pragma unroll
        for (int i = 3; i >= 0; --i) dxv[i] = dxv[i + 1] + tv[i];
#pragma unroll
        for (int j = 0; j < 9; ++j) {
            float pxf = (float)px + dxv[j];
            float x0f = floorf(pxf);
            float fx  = pxf - x0f;
            int   x0  = (int)x0f;
            float s0f = (x0 >= 0 && x0 < WID) ? 1.f - fx : 0.f;
            float s1f = (x0 >= -1 && x0 < WID - 1) ? fx : 0.f;
            unsigned h0 = f2h(s0f), h1 = f2h(s1f);
            P0h[j][t] = h0 | (h0 << 16);
            P1h[j][t] = h1 | (h1 << 16);
            int xi0 = min(max(x0, 0), WID - 1);
            int xi1 = min(max(x0 + 1, 0), WID - 1);
            PXI[j][t] = xi0 | (xi1 << 16);
        }
    }
    __syncthreads();

    f32x4 acc[5];
#pragma unroll
    for (int i = 0; i < 5; ++i) acc[i] = (f32x4){0.f, 0.f, 0.f, 0.f};

    int klo = 4 - h;   if (klo < 0) klo = 0;
    int khi = 163 - h; if (khi > 8) khi = 8;

    int    A[10], Bv[10];
    f16x8  wpa, wpb;
    int    pxb = t >> 5, ci = t & 31;

#define PF(kk)                                                                  \
    {                                                                           \
        int py = h + (kk) - 4;                                                  \
        const int* row = (const int*)xbT + (b * HEI + py) * (WID * 32);         \
        _Pragma("unroll")                                                       \
        for (int u = 0; u < 10; ++u) {                                          \
            int xi = PXI[kk][pxb + u * 8];                                      \
            A[u]  = row[(xi & 0xffff) * 32 + ci];                               \
            Bv[u] = row[(xi >> 16) * 32 + ci];                                  \
        }                                                                       \
        wpa = *(const f16x8*)(wtA + ((((kk) * 2 + 0) * 4 + wave) * 64 + lane) * 8); \
        wpb = *(const f16x8*)(wtA + ((((kk) * 2 + 1) * 4 + wave) * 64 + lane) * 8); \
    }

    PF(klo);
    int buf = 0;

    for (int k = klo; k <= khi; ++k) {
        int* Sb = S[buf];
        // ---- build S[buf] from prefetched registers: packed-f16 lerp ----
#pragma unroll
        for (int u = 0; u < 10; ++u) {
            int pxl = pxb + u * 8;
            HU sa, sb, av, bv, r;
            sa.u = P0h[k][pxl];
            sb.u = P1h[k][pxl];
            av.u = (unsigned)A[u];
            bv.u = (unsigned)Bv[u];
            r.h  = __hfma2(sb.h, bv.h, __hmul2(sa.h, av.h));
            Sb[pxl * 36 + ci] = (int)r.u;
        }
        __syncthreads();                           // S[buf] ready (1 barrier/tap)

        f16x8 wf0 = wpa, wf1 = wpb;
        if (k < khi) PF(k + 1);                    // prefetch overlaps consume

        // ---- consume: 5 pxt x 2 ch MFMAs per wave ----
#pragma unroll
        for (int pxt = 0; pxt < 5; ++pxt) {
            const int* sp = &Sb[(pxt * 16 + l15) * 36];
            U4 u0, u1;
            *(int4*)u0.i = *(const int4*)(sp + q * 4);
            *(int4*)u1.i = *(const int4*)(sp + 16 + q * 4);
            acc[pxt] = __builtin_amdgcn_mfma_f32_16x16x32_f16(wf0, u0.v, acc[pxt], 0, 0, 0);
            acc[pxt] = __builtin_amdgcn_mfma_f32_16x16x32_f16(wf1, u1.v, acc[pxt], 0, 0, 0);
        }
        buf ^= 1;
    }
#undef PF

    // ---- epilogue ----
    float bd[4];
#pragma unroll
    for (int r = 0; r < 4; ++r) bd[r] = b_def[wave * 16 + q * 4 + r];
#pragma unroll
    for (int pxt = 0; pxt < 5; ++pxt) {
#pragma unroll
        for (int r = 0; r < 4; ++r) {
            int o = wave * 16 + q * 4 + r;
            out[(b * COUT + o) * HW + h * WID + p0 + pxt * 16 + l15] = acc[pxt][r] + bd[r];
        }
    }
}

// ---------------------------------------------------------------------------
extern "C" void kernel_launch(void* const* d_in, const int* in_sizes, int n_in,
                              void* d_out, int out_size, void* d_ws, size_t ws_size,
                              hipStream_t stream) {
    const float* x     = (const float*)d_in[0];
    const float* w_off = (const float*)d_in[1];
    const float* b_off = (const float*)d_in[2];
    const float* gamma = (const float*)d_in[3];
    const float* beta  = (const float*)d_in[4];
    const float* w_def = (const float*)d_in[5];
    const float* b_def = (const float*)d_in[6];
    float* out = (float*)d_out;

    // workspace layout: ~17.0 MB
    float* off_odd       = (float*)d_ws;                    // 921600 f
    float* stats         = off_odd + 921600;                // 32 f
    unsigned short* wtA  = (unsigned short*)(stats + 32);   // 36864 u16
    unsigned short* wofA = wtA + 36864;                     // 9216 u16
    unsigned short* xbT  = wofA + 9216;                     // 6553600 u16

    p0_prep<<<641, 256, 0, stream>>>(x, w_def, w_off, xbT, wtA, wofA, stats);
    k1_offconv_mfma<<<640, 256, 0, stream>>>(xbT, wofA, b_off, off_odd, stats);
    k4_deform_mfma<<<1280, 256, 0, stream>>>(xbT, off_odd, stats, gamma, beta,
                                             wtA, b_def, out);
}

// Round 8
// 153.105 us; speedup vs baseline: 1.0168x; 1.0168x over previous
//
#include <hip/hip_runtime.h>
#include <hip/hip_fp16.h>
#include <math.h>

#define HW    25600
#define WID   160
#define HEI   160
#define BB    4
#define CIN   64
#define COUT  64
#define NBN   102400
#define TSTR  162     // p0 LDS tile stride in shorts: int-stride 81 == 17 mod 32

typedef _Float16 f16x8 __attribute__((ext_vector_type(8)));
typedef float    f32x4 __attribute__((ext_vector_type(4)));

union U4 { int i[4]; f16x8 v; };
union HU { unsigned u; __half2 h; };

__device__ __forceinline__ unsigned short f2h(float f) {
    return __half_as_ushort(__float2half(f));   // RNE
}

// fast tanh: 1 - 2/(e^{2x}+1), safe at +-inf (rcp(inf)=0 -> 1)
__device__ __forceinline__ float ftanh(float x) {
    float e = __builtin_amdgcn_exp2f(x * 2.8853900817779268f);  // 2*log2(e)
    return 1.0f - 2.0f * __builtin_amdgcn_rcpf(e + 1.0f);
}

// ---------------------------------------------------------------------------
// P0: prep. blocks 0..639: transpose x[b][c][h][w] fp32 -> xbT[b][h][w][c] fp16
//     block 640: pack w_def + w_off(odd) into MFMA A-fragment order (f16) + zero stats
// ---------------------------------------------------------------------------
__global__ __launch_bounds__(256) void p0_prep(
        const float* __restrict__ x, const float* __restrict__ w_def,
        const float* __restrict__ w_off,
        unsigned short* __restrict__ xbT, unsigned short* __restrict__ wtA,
        unsigned short* __restrict__ wofA, float* __restrict__ stats) {
    int t = threadIdx.x;
    int blk = blockIdx.x;
    if (blk == 640) {
        for (int u = 0; u < 144; ++u) {
            int idx = t + u * 256;                 // < 36864
            int k = idx >> 12;
            int r = idx & 4095;
            int chalf = r >> 11;
            int og = (r >> 9) & 3;
            int L = (r >> 3) & 63;
            int j = idx & 7;
            int o = og * 16 + (L & 15);
            int c = chalf * 32 + (L >> 4) * 8 + j;
            wtA[idx] = f2h(w_def[(o * CIN + c) * 9 + k]);
        }
        for (int u = 0; u < 36; ++u) {
            int idx = t + u * 256;                 // < 9216
            int jj = idx & 7;
            int L  = (idx >> 3) & 63;
            int ch = (idx >> 9) & 1;
            int k  = idx >> 10;
            int j  = L & 15;
            int c  = ch * 32 + (L >> 4) * 8 + jj;
            wofA[idx] = (j < 9) ? f2h(w_off[((2 * j + 1) * CIN + c) * 9 + k])
                                : (unsigned short)0;
        }
        if (t < 32) stats[t] = 0.f;
        return;
    }
    __shared__ __align__(16) unsigned short tile[CIN * TSTR];  // [c][w]
    int b = blk / HEI, h = blk % HEI;
    const float* xp = x + (b * CIN) * HW + h * WID;
    unsigned* ti = (unsigned*)tile;
#pragma unroll
    for (int u = 0; u < 10; ++u) {
        int e = t + u * 256;                       // 0..2559 = 64 c x 40 quads
        int c = e / 40, wq = e - c * 40;
        const float4 v = *(const float4*)(xp + c * HW + 4 * wq);
        unsigned p01 = f2h(v.x) | ((unsigned)f2h(v.y) << 16);
        unsigned p23 = f2h(v.z) | ((unsigned)f2h(v.w) << 16);
        ti[81 * c + 2 * wq]     = p01;
        ti[81 * c + 2 * wq + 1] = p23;
    }
    __syncthreads();
    unsigned* dst = (unsigned*)(xbT + (b * HEI + h) * (WID * 64));
#pragma unroll
    for (int u = 0; u < 20; ++u) {
        int e = t + u * 256;                       // 0..5119 = 160 w x 32 cpair
        int w = e >> 5, cp = e & 31;
        unsigned lo = tile[(2 * cp) * TSTR + w];
        unsigned hi = tile[(2 * cp + 1) * TSTR + w];
        dst[e] = lo | (hi << 16);
    }
}

// ---------------------------------------------------------------------------
// K1 v3: offset conv via f16 MFMA. 1280 half-row blocks x 320 threads:
// 5 waves, each owns exactly one 16-px tile (balanced), 25 waves/CU.
// ---------------------------------------------------------------------------
__global__ __launch_bounds__(320) void k1_offconv_mfma(
        const unsigned short* __restrict__ xbT,
        const unsigned short* __restrict__ wofA,
        const float* __restrict__ b_off,
        float* __restrict__ off_odd, float* __restrict__ stats) {
    int t = threadIdx.x;
    int blk = blockIdx.x;                          // 0..1279
    int xcd = blk & 7;
    int idx = blk >> 3;                            // 0..159
    int b   = idx / 40;
    int r2  = idx - b * 40;                        // 0..39
    int h   = xcd * 20 + (r2 >> 1);
    int p0  = (r2 & 1) * 80;
    int wave = t >> 6, lane = t & 63;
    int l15 = lane & 15, q = lane >> 4;
    int px  = p0 + wave * 16 + l15;

    f32x4 acc = (f32x4){0.f, 0.f, 0.f, 0.f};

    int klo = 4 - h;   if (klo < 0) klo = 0;
    int khi = 163 - h; if (khi > 8) khi = 8;

    for (int k = klo; k <= khi; ++k) {
        int py = h + k - 4;
        const unsigned short* sp = xbT + (b * HEI + py) * (WID * 64) + px * 64;
        f16x8 a0 = *(const f16x8*)(wofA + ((k * 2 + 0) * 64 + lane) * 8);
        f16x8 a1 = *(const f16x8*)(wofA + ((k * 2 + 1) * 64 + lane) * 8);
        f16x8 b0 = *(const f16x8*)(sp + q * 8);
        f16x8 b1 = *(const f16x8*)(sp + 32 + q * 8);
        acc = __builtin_amdgcn_mfma_f32_16x16x32_f16(a0, b0, acc, 0, 0, 0);
        acc = __builtin_amdgcn_mfma_f32_16x16x32_f16(a1, b1, acc, 0, 0, 0);
    }

    // epilogue: bias, store, fused BN stats
    float sS[4] = {0.f, 0.f, 0.f, 0.f}, sQ[4] = {0.f, 0.f, 0.f, 0.f};
#pragma unroll
    for (int r = 0; r < 4; ++r) {
        int j = q * 4 + r;
        if (j < 9) {
            float v = acc[r] + b_off[2 * j + 1];
            off_odd[(b * 9 + j) * HW + h * WID + px] = v;
            sS[r] = v; sQ[r] = v * v;
        }
    }
#pragma unroll
    for (int o = 1; o < 16; o <<= 1) {
#pragma unroll
        for (int r = 0; r < 4; ++r) {
            sS[r] += __shfl_xor(sS[r], o);
            sQ[r] += __shfl_xor(sQ[r], o);
        }
    }
    __shared__ float redS[5][16], redQ[5][16];
    if (l15 == 0) {
#pragma unroll
        for (int r = 0; r < 4; ++r) {
            int j = q * 4 + r;
            if (j < 9) { redS[wave][j] = sS[r]; redQ[wave][j] = sQ[r]; }
        }
    }
    __syncthreads();
    if (t < 18) {
        int j = (t < 9) ? t : t - 9;
        float v = 0.f;
#pragma unroll
        for (int w = 0; w < 5; ++w)
            v += (t < 9) ? redS[w][j] : redQ[w][j];
        atomicAdd(&stats[t], v);
    }
}

// ---------------------------------------------------------------------------
// K4 v6: deformable conv via f16 MFMA.
//  - int4-granular cooperative build: thread lerps 8 channels per step
//    (2.5 int4-pairs/tap vs 10 int-pairs) -> ~2x less VALU, 4x less ds_b32
//  - uniform 9-tap loop: row validity folded into s0/s1 (=0), py clamped
//  - fast tanh in prep; dbuf S, 1 barrier/tap; batched register prefetch
// ---------------------------------------------------------------------------
__global__ __launch_bounds__(256, 5) void k4_deform_mfma(
        const unsigned short* __restrict__ xbT,
        const float* __restrict__ off_odd,
        const float* __restrict__ stats,
        const float* __restrict__ gamma,
        const float* __restrict__ beta,
        const unsigned short* __restrict__ wtA,
        const float* __restrict__ b_def,
        float* __restrict__ out) {
    __shared__ __align__(16) int S[2][80 * 36];    // samples, frag layout, dbuf
    __shared__ unsigned P0h[9][80], P1h[9][80];    // packed (s,s) half2
    __shared__ int      PXI[9][80];                // xi0 | xi1<<16

    int t   = threadIdx.x;
    int blk = blockIdx.x;                          // 0..1279
    int xcd = blk & 7;
    int idx = blk >> 3;                            // 0..159
    int b   = idx / 40;
    int r2  = idx - b * 40;                        // 0..39
    int h   = xcd * 20 + (r2 >> 1);
    int p0  = (r2 & 1) * 80;
    int wave = t >> 6, lane = t & 63;
    int l15 = lane & 15, q = lane >> 4;

    // ---- prep: offsets -> sampling params (fused BN+tanh+convert) ----
    if (t < 80) {
        int px = p0 + t;
        float tv[9];
#pragma unroll
        for (int j = 0; j < 9; ++j) {
            float mean = stats[j] * (1.0f / NBN);
            float var  = stats[9 + j] * (1.0f / NBN) - mean * mean;
            float inv  = rsqrtf(var + 1e-5f);
            float v = off_odd[(b * 9 + j) * HW + h * WID + px];
            tv[j] = ftanh((v - mean) * inv * gamma[2 * j + 1] + beta[2 * j + 1]);
        }
        float dxv[9];
        dxv[4] = tv[4];
#pragma unroll
        for (int i = 5; i < 9; ++i) dxv[i] = dxv[i - 1] + tv[i];
#pragma unroll
        for (int i = 3; i >= 0; --i) dxv[i] = dxv[i + 1] + tv[i];
#pragma unroll
        for (int j = 0; j < 9; ++j) {
            int py = h + j - 4;
            bool rowok = (py >= 0) && (py < HEI);
            float pxf = (float)px + dxv[j];
            float x0f = floorf(pxf);
            float fx  = pxf - x0f;
            int   x0  = (int)x0f;
            float s0f = (rowok && x0 >= 0 && x0 < WID) ? 1.f - fx : 0.f;
            float s1f = (rowok && x0 >= -1 && x0 < WID - 1) ? fx : 0.f;
            unsigned h0 = f2h(s0f), h1 = f2h(s1f);
            P0h[j][t] = h0 | (h0 << 16);
            P1h[j][t] = h1 | (h1 << 16);
            int xi0 = min(max(x0, 0), WID - 1);
            int xi1 = min(max(x0 + 1, 0), WID - 1);
            PXI[j][t] = xi0 | (xi1 << 16);
        }
    }
    __syncthreads();

    f32x4 acc[5];
#pragma unroll
    for (int i = 0; i < 5; ++i) acc[i] = (f32x4){0.f, 0.f, 0.f, 0.f};

    // build-unit mapping: idx = u*256 + t (u=0,1 full, u=2 for t<128)
    // px = idx>>3 (0..79), c4 = idx&7 (int4 within 64-ch row)
    int4     A4[3], B4[3];
    unsigned sa[3], sb[3];
    f16x8    wpa, wpb;

#define PF(kk)                                                                  \
    {                                                                           \
        int pyc = min(max(h + (kk) - 4, 0), HEI - 1);                           \
        const int4* rowI4 = (const int4*)(xbT + (b * HEI + pyc) * (WID * 64));  \
        _Pragma("unroll")                                                       \
        for (int u = 0; u < 3; ++u) {                                           \
            if (u < 2 || t < 128) {                                             \
                int id = t + u * 256;                                           \
                int pxl = id >> 3, c4 = id & 7;                                 \
                int xi = PXI[kk][pxl];                                          \
                sa[u] = P0h[kk][pxl];                                           \
                sb[u] = P1h[kk][pxl];                                           \
                A4[u] = rowI4[(xi & 0xffff) * 8 + c4];                          \
                B4[u] = rowI4[(xi >> 16) * 8 + c4];                             \
            }                                                                   \
        }                                                                       \
        wpa = *(const f16x8*)(wtA + ((((kk) * 2 + 0) * 4 + wave) * 64 + lane) * 8); \
        wpb = *(const f16x8*)(wtA + ((((kk) * 2 + 1) * 4 + wave) * 64 + lane) * 8); \
    }

    PF(0);
    int buf = 0;

    for (int k = 0; k < 9; ++k) {
        int* Sb = S[buf];
        // ---- build S[buf]: packed-f16 lerp of int4 spans ----
#pragma unroll
        for (int u = 0; u < 3; ++u) {
            if (u < 2 || t < 128) {
                int id = t + u * 256;
                int pxl = id >> 3, c4 = id & 7;
                HU sah, sbh; sah.u = sa[u]; sbh.u = sb[u];
                int4 r4;
                HU a, bb, r;
#pragma unroll
                for (int ii = 0; ii < 4; ++ii) {
                    a.u  = (unsigned)(&A4[u].x)[ii];
                    bb.u = (unsigned)(&B4[u].x)[ii];
                    r.h  = __hfma2(sbh.h, bb.h, __hmul2(sah.h, a.h));
                    (&r4.x)[ii] = (int)r.u;
                }
                *(int4*)(Sb + pxl * 36 + (c4 << 2)) = r4;
            }
        }
        __syncthreads();                           // S[buf] ready (1 barrier/tap)

        f16x8 wf0 = wpa, wf1 = wpb;
        if (k < 8) PF(k + 1);                      // prefetch overlaps consume

        // ---- consume: 5 pxt x 2 ch MFMAs per wave ----
#pragma unroll
        for (int pxt = 0; pxt < 5; ++pxt) {
            const int* sp = &Sb[(pxt * 16 + l15) * 36];
            U4 u0, u1;
            *(int4*)u0.i = *(const int4*)(sp + q * 4);
            *(int4*)u1.i = *(const int4*)(sp + 16 + q * 4);
            acc[pxt] = __builtin_amdgcn_mfma_f32_16x16x32_f16(wf0, u0.v, acc[pxt], 0, 0, 0);
            acc[pxt] = __builtin_amdgcn_mfma_f32_16x16x32_f16(wf1, u1.v, acc[pxt], 0, 0, 0);
        }
        buf ^= 1;
    }
#undef PF

    // ---- epilogue ----
    float bd[4];
#pragma unroll
    for (int r = 0; r < 4; ++r) bd[r] = b_def[wave * 16 + q * 4 + r];
#pragma unroll
    for (int pxt = 0; pxt < 5; ++pxt) {
#pragma unroll
        for (int r = 0; r < 4; ++r) {
            int o = wave * 16 + q * 4 + r;
            out[(b * COUT + o) * HW + h * WID + p0 + pxt * 16 + l15] = acc[pxt][r] + bd[r];
        }
    }
}

// ---------------------------------------------------------------------------
extern "C" void kernel_launch(void* const* d_in, const int* in_sizes, int n_in,
                              void* d_out, int out_size, void* d_ws, size_t ws_size,
                              hipStream_t stream) {
    const float* x     = (const float*)d_in[0];
    const float* w_off = (const float*)d_in[1];
    const float* b_off = (const float*)d_in[2];
    const float* gamma = (const float*)d_in[3];
    const float* beta  = (const float*)d_in[4];
    const float* w_def = (const float*)d_in[5];
    const float* b_def = (const float*)d_in[6];
    float* out = (float*)d_out;

    // workspace layout: ~17.0 MB
    float* off_odd       = (float*)d_ws;                    // 921600 f
    float* stats         = off_odd + 921600;                // 32 f
    unsigned short* wtA  = (unsigned short*)(stats + 32);   // 36864 u16
    unsigned short* wofA = wtA + 36864;                     // 9216 u16
    unsigned short* xbT  = wofA + 9216;                     // 6553600 u16

    p0_prep<<<641, 256, 0, stream>>>(x, w_def, w_off, xbT, wtA, wofA, stats);
    k1_offconv_mfma<<<1280, 320, 0, stream>>>(xbT, wofA, b_off, off_odd, stats);
    k4_deform_mfma<<<1280, 256, 0, stream>>>(xbT, off_odd, stats, gamma, beta,
                                             wtA, b_def, out);
}